// Round 14
// baseline (226.390 us; speedup 1.0000x reference)
//
#include <hip/hip_runtime.h>
#include <cstdint>

// Problem constants (fixed by setup_inputs)
#define B_   4
#define N_   50000
#define K_   27
#define P_   (B_ * N_)           // 200000 points
#define L_   (P_ * K_)           // 5400000 flat entries (64 | L_)
#define S_   130                 // per-dim encoding stride
#define PL_  (S_ * S_)           // 16900 plane stride
#define KS_  (B_ * S_ * S_ * S_) // 8788000 table cells (div by 4)
#define W_   (L_ / 64)           // 84375 bitmap words
#define NBW  ((W_ + 255) / 256)  // 330 word-scan blocks
#define BIGP 0x7f7f7f7f          // empty marker (stencil adds <=26, stays < 2^31)
#define NBIN (B_ * S_)           // 520 (b, x+1) plane bins

// zero the 520-bin histogram (tiny)
__global__ __launch_bounds__(1024) void k_zero(int* __restrict__ hist) {
    int i = threadIdx.x;
    if (i < NBIN) hist[i] = 0;
}

// histogram points by (b, x+1) plane
__global__ __launch_bounds__(256) void k_hist(const int* __restrict__ coords,
                                              const int* __restrict__ bidx,
                                              int* __restrict__ hist) {
    int p = blockIdx.x * blockDim.x + threadIdx.x;
    if (p >= P_) return;
    atomicAdd(&hist[bidx[p] * S_ + coords[3 * p] + 1], 1);
}

// exclusive scan of 520 bins -> binoff[0..520]; cursor = copy
__global__ __launch_bounds__(1024) void k_hscan(const int* __restrict__ hist,
                                                int* __restrict__ binoff,
                                                int* __restrict__ cursor) {
    __shared__ int sh[1024];
    int i = threadIdx.x;
    int v = (i < NBIN) ? hist[i] : 0;
    sh[i] = v;
    __syncthreads();
    for (int off = 1; off < 1024; off <<= 1) {
        int t = (i >= off) ? sh[i - off] : 0;
        __syncthreads();
        sh[i] += t;
        __syncthreads();
    }
    if (i < NBIN) { binoff[i] = sh[i] - v; cursor[i] = sh[i] - v; }
    if (i == 0) binoff[NBIN] = sh[1023];
}

// scatter points into per-plane compact lists; also store packed coords
__global__ __launch_bounds__(256) void k_scatter(const int* __restrict__ coords,
                                                 const int* __restrict__ bidx,
                                                 int* __restrict__ cursor,
                                                 int2* __restrict__ pts,
                                                 int* __restrict__ bpt) {
    int p = blockIdx.x * blockDim.x + threadIdx.x;
    if (p >= P_) return;
    int b = bidx[p];
    int x = coords[3 * p + 0] + 1;   // 1..128
    int y = coords[3 * p + 1] + 1;
    int z = coords[3 * p + 2] + 1;
    bpt[p] = (b << 24) | (x << 16) | (y << 8) | z;
    int slot = atomicAdd(&cursor[b * S_ + x], 1);
    pts[slot] = make_int2(y * S_ + z, p << 5);
}

// Fused z+y min-plus stencil; plane built IN LDS from the bin's point list
// (no dense-table init / global atomics / 35MB plane read).
//   z: center +1 ; from z-1 +2 ; from z+1 +0
//   y: center +3 ; from y-1 +6 ; from y+1 +0
__global__ __launch_bounds__(512) void k_zy(const int2* __restrict__ pts,
                                            const int* __restrict__ binoff,
                                            int* __restrict__ dst) {
    __shared__ int pl[PL_];   // 67.6 KB
    __shared__ int tz[PL_];   // 67.6 KB (135 KB total)
    int blk = blockIdx.x;     // b*S_ + x
    for (int i = threadIdx.x; i < PL_; i += 512) pl[i] = BIGP;
    __syncthreads();
    int s = binoff[blk], e = binoff[blk + 1];
    for (int i = s + threadIdx.x; i < e; i += 512) {
        int2 q = pts[i];
        atomicMin(&pl[q.x], q.y);
    }
    __syncthreads();
    for (int i = threadIdx.x; i < PL_; i += 512) {
        int z = i % S_;
        int v = pl[i] + 1;
        if (z > 0)      v = min(v, pl[i - 1] + 2);
        if (z < S_ - 1) v = min(v, pl[i + 1]);
        tz[i] = v;
    }
    __syncthreads();
    int4* d4 = (int4*)(dst + (size_t)blk * PL_);
    for (int i = threadIdx.x; i < PL_ / 4; i += 512) {
        int4 o;
        int base = 4 * i;
        #pragma unroll
        for (int j = 0; j < 4; ++j) {
            int idx = base + j;
            int y = idx / S_;
            int v = tz[idx] + 3;
            if (y > 0)      v = min(v, tz[idx - S_] + 6);
            if (y < S_ - 1) v = min(v, tz[idx + S_]);
            ((int*)&o)[j] = v;
        }
        d4[i] = o;
    }
}

// x min-plus stencil, int4-vectorized (R9-proven).
//   center +9 ; from cx-1 +18 ; from cx+1 +0
__global__ __launch_bounds__(256) void k_x(const int4* __restrict__ src,
                                           int4* __restrict__ dst) {
    const int n4 = KS_ / 4;
    int i = blockIdx.x * blockDim.x + threadIdx.x;
    if (i >= n4) return;
    int x = (i / (PL_ / 4)) % S_;
    int4 c = src[i];
    int4 v = make_int4(c.x + 9, c.y + 9, c.z + 9, c.w + 9);
    if (x > 0) {
        int4 m = src[i - PL_ / 4];
        v.x = min(v.x, m.x + 18); v.y = min(v.y, m.y + 18);
        v.z = min(v.z, m.z + 18); v.w = min(v.w, m.w + 18);
    }
    if (x < S_ - 1) {
        int4 pp = src[i + PL_ / 4];
        v.x = min(v.x, pp.x); v.y = min(v.y, pp.y);
        v.z = min(v.z, pp.z); v.w = min(v.w, pp.w);
    }
    dst[i] = v;
}

// THE random pass (R9-proven): gather m32 per l, ballot -> bitmap;
// out0/out2 fills ride under the fetch-bound gather.
__global__ __launch_bounds__(256) void k_gather(const int* __restrict__ bpt,
                                                const int* __restrict__ M,
                                                int* __restrict__ mArr,
                                                unsigned long long* __restrict__ bitmap,
                                                int* __restrict__ out0,
                                                int* __restrict__ out2) {
    int l = blockIdx.x * blockDim.x + threadIdx.x;
    if (l >= L_) return;
    int p = l / K_;
    int k = l - p * K_;
    out0[l] = p - (p / N_) * N_;   // n
    out2[l] = k;
    unsigned u = (unsigned)bpt[p];
    int b = u >> 24, x = (u >> 16) & 255, y = (u >> 8) & 255, z = u & 255;
    int dx = k / 9, dy = (k / 3) % 3, dz = k - (k / 3) * 3;
    int cx = x + dx - 1, cy = y + dy - 1, cz = z + dz - 1;   // 0..129
    int idx = ((b * S_ + cx) * S_ + cy) * S_ + cz;
    int m32 = M[idx];
    mArr[l] = m32;
    unsigned long long bal = __ballot(m32 == ((p << 5) | k));
    if ((threadIdx.x & 63) == 0) bitmap[l >> 6] = bal;
}

// per-word popcount + per-block exclusive scan over 84375 words
__global__ __launch_bounds__(256) void k_scan_words(const unsigned long long* __restrict__ bitmap,
                                                    int* __restrict__ wpre,
                                                    int* __restrict__ bsum) {
    __shared__ int sh[256];
    int w = blockIdx.x * 256 + threadIdx.x;
    int c = (w < W_) ? __popcll(bitmap[w]) : 0;
    sh[threadIdx.x] = c;
    __syncthreads();
    for (int off = 1; off < 256; off <<= 1) {
        int t = (threadIdx.x >= off) ? sh[threadIdx.x - off] : 0;
        __syncthreads();
        sh[threadIdx.x] += t;
        __syncthreads();
    }
    if (w < W_) wpre[w] = sh[threadIdx.x] - c;        // exclusive within block
    if (threadIdx.x == 255) bsum[blockIdx.x] = sh[255];
}

// single-block exclusive scan over the 330 block sums; emits num_unique
__global__ __launch_bounds__(512) void k_scan_block(int* __restrict__ bsum,
                                                    int* __restrict__ num_unique_out) {
    __shared__ int sh[512];
    int i = threadIdx.x;
    int v = (i < NBW) ? bsum[i] : 0;
    sh[i] = v;
    __syncthreads();
    for (int off = 1; off < 512; off <<= 1) {
        int t = (i >= off) ? sh[i - off] : 0;
        __syncthreads();
        sh[i] += t;
        __syncthreads();
    }
    if (i < NBW) bsum[i] = sh[i] - v;                 // global exclusive prefix
    if (i == 0) num_unique_out[0] = sh[511];
}

// rank via bitmap popcount (bitmap+wpre ~1.3MB, L2-resident); valid outkey
// rows written once; tail rows (>= num_unique) written -1 here (disjoint).
__global__ __launch_bounds__(256) void k_finalize(const int* __restrict__ coords,
                                                  const int* __restrict__ koffs,
                                                  const unsigned long long* __restrict__ bitmap,
                                                  const int* __restrict__ wpre,
                                                  const int* __restrict__ bsum,
                                                  const int* __restrict__ numuniq,
                                                  int* __restrict__ out1,   // holds m32, becomes output_idx
                                                  int* __restrict__ outkey) {
    int l = blockIdx.x * blockDim.x + threadIdx.x;
    if (l >= L_) return;
    int m32 = out1[l];
    int m = (m32 >> 5) * K_ + (m32 & 31);
    int w = m >> 6;
    unsigned long long word = bitmap[w];
    unsigned long long mask = (1ull << (m & 63)) - 1ull;
    int rank = wpre[w] + bsum[w >> 8] + (int)__popcll(word & mask);
    out1[l] = rank;
    if (m == l) {
        int p = l / K_;
        int k = l - p * K_;
        outkey[3 * rank + 0] = coords[3 * p + 0] + koffs[3 * k + 0];
        outkey[3 * rank + 1] = coords[3 * p + 1] + koffs[3 * k + 1];
        outkey[3 * rank + 2] = coords[3 * p + 2] + koffs[3 * k + 2];
    }
    if (l >= numuniq[0]) {
        outkey[3 * l + 0] = -1;
        outkey[3 * l + 1] = -1;
        outkey[3 * l + 2] = -1;
    }
}

extern "C" void kernel_launch(void* const* d_in, const int* in_sizes, int n_in,
                              void* d_out, int out_size, void* d_ws, size_t ws_size,
                              hipStream_t stream) {
    const int* coords = (const int*)d_in[0];   // [B,N,3] int32
    const int* bidx   = (const int*)d_in[1];   // [B,N]   int32
    const int* koffs  = (const int*)d_in[2];   // [27,3]  int32

    int* out      = (int*)d_out;
    int* out0     = out;            // input_idx      [L]
    int* out1     = out + L_;       // output_idx     [L] (holds m32 first)
    int* out2     = out + 2 * L_;   // rel_pos_idx    [L]
    int* outkey   = out + 3 * L_;   // output_key     [L,3]
    int* numuniq  = out + 6 * L_;   // num_unique     [1]

    // ws (~40 MB): M | bitmap | wpre | bsum | bpt | hist | binoff | cursor | pts
    int* M = (int*)d_ws;                                       // KS_ ints
    unsigned long long* bitmap = (unsigned long long*)(M + KS_); // W_ u64 (8B aligned)
    int* wpre   = (int*)(bitmap + W_);                         // W_ ints
    int* bsum   = wpre + W_;                                   // NBW ints
    int* bpt    = bsum + NBW;                                  // P_ ints
    int* hist   = bpt + P_;                                    // NBIN
    int* binoff = hist + NBIN;                                 // NBIN+1
    int* cursor = binoff + NBIN + 1;                           // NBIN (+pad to even)
    int2* pts   = (int2*)(cursor + NBIN + 1);                  // P_ int2 (8B aligned)

    // stencil ping buffer A in the (not-yet-written) outkey region:
    // KS_ ints <= 3*L_ ints; fully consumed by k_x before k_finalize writes outkey.
    int* A = outkey;

    k_zero       <<<1, 1024, 0, stream>>>(hist);
    k_hist       <<<(P_ + 255) / 256, 256, 0, stream>>>(coords, bidx, hist);
    k_hscan      <<<1, 1024, 0, stream>>>(hist, binoff, cursor);
    k_scatter    <<<(P_ + 255) / 256, 256, 0, stream>>>(coords, bidx, cursor, pts, bpt);
    k_zy         <<<NBIN, 512, 0, stream>>>(pts, binoff, A);                 // LDS-built planes -> A
    k_x          <<<(KS_ / 4 + 255) / 256, 256, 0, stream>>>((const int4*)A, (int4*)M);
    k_gather     <<<(L_ + 255) / 256, 256, 0, stream>>>(bpt, M, out1, bitmap, out0, out2);
    k_scan_words <<<NBW, 256, 0, stream>>>(bitmap, wpre, bsum);
    k_scan_block <<<1, 512, 0, stream>>>(bsum, numuniq);
    k_finalize   <<<(L_ + 255) / 256, 256, 0, stream>>>(coords, koffs, bitmap, wpre, bsum,
                                                        numuniq, out1, outkey);
}

// Round 15
// 143.857 us; speedup vs baseline: 1.5737x; 1.5737x over previous
//
#include <hip/hip_runtime.h>
#include <cstdint>

// Problem constants (fixed by setup_inputs)
#define B_   4
#define N_   50000
#define K_   27
#define P_   (B_ * N_)           // 200000 points
#define L_   (P_ * K_)           // 5400000 flat entries (64 | L_)
#define S_   130                 // per-dim encoding stride
#define PL_  (S_ * S_)           // 16900 plane stride
#define KS_  (B_ * S_ * S_ * S_) // 8788000 linear table cells
#define W_   (L_ / 64)           // 84375 bitmap words
#define NBW  ((W_ + 255) / 256)  // 330 word-scan blocks
#define BIGP 0x7f7f7f7f          // empty marker (stencil adds <=26, stays < 2^31)

// table init (int4 BIGP fill); bitmap needs no init (fully ballot-written)
__global__ __launch_bounds__(256) void k_init(int4* __restrict__ T4) {
    const int n4 = KS_ / 4;
    int4 v = make_int4(BIGP, BIGP, BIGP, BIGP);
    for (int i = blockIdx.x * blockDim.x + threadIdx.x; i < n4; i += gridDim.x * blockDim.x)
        T4[i] = v;
}

// point table: P1[cell(p)] = min 32*p  (200k atomics, uncontended-ish)
// also stores each point's packed padded coords for the gather pass.
__global__ __launch_bounds__(256) void k_ptab(const int* __restrict__ coords,
                                              const int* __restrict__ bidx,
                                              int* __restrict__ P1,
                                              int* __restrict__ bpt) {
    int p = blockIdx.x * blockDim.x + threadIdx.x;
    if (p >= P_) return;
    int b = bidx[p];
    int x = coords[3 * p + 0] + 1;   // 1..128
    int y = coords[3 * p + 1] + 1;
    int z = coords[3 * p + 2] + 1;
    bpt[p] = (b << 24) | (x << 16) | (y << 8) | z;
    atomicMin(&P1[((b * S_ + x) * S_ + y) * S_ + z], p << 5);
}

// Fused z+y min-plus stencil, one block per (b,cx) plane staged in LDS.
//   z: center +1 ; from z-1 +2 ; from z+1 +0
//   y: center +3 ; from y-1 +6 ; from y+1 +0
__global__ __launch_bounds__(512) void k_zy(const int* __restrict__ src,
                                            int* __restrict__ dst) {
    __shared__ int pl[PL_];   // 67.6 KB
    __shared__ int tz[PL_];   // 67.6 KB (135 KB total)
    const int4* s4 = (const int4*)(src + (size_t)blockIdx.x * PL_);
    int4* d4       = (int4*)(dst + (size_t)blockIdx.x * PL_);
    int4* pl4      = (int4*)pl;
    for (int i = threadIdx.x; i < PL_ / 4; i += 512) pl4[i] = s4[i];
    __syncthreads();
    for (int i = threadIdx.x; i < PL_; i += 512) {
        int z = i % S_;
        int v = pl[i] + 1;
        if (z > 0)      v = min(v, pl[i - 1] + 2);
        if (z < S_ - 1) v = min(v, pl[i + 1]);
        tz[i] = v;
    }
    __syncthreads();
    for (int i = threadIdx.x; i < PL_ / 4; i += 512) {
        int4 o;
        int base = 4 * i;
        #pragma unroll
        for (int j = 0; j < 4; ++j) {
            int idx = base + j;
            int y = idx / S_;
            int v = tz[idx] + 3;
            if (y > 0)      v = min(v, tz[idx - S_] + 6);
            if (y < S_ - 1) v = min(v, tz[idx + S_]);
            ((int*)&o)[j] = v;
        }
        d4[i] = o;
    }
}

// x min-plus stencil, int4-vectorized, no atomics.
//   center +9 ; from cx-1 +18 ; from cx+1 +0
__global__ __launch_bounds__(256) void k_x(const int4* __restrict__ src,
                                           int4* __restrict__ dst) {
    const int n4 = KS_ / 4;
    int i = blockIdx.x * blockDim.x + threadIdx.x;
    if (i >= n4) return;
    int x = (i / (PL_ / 4)) % S_;
    int4 c = src[i];
    int4 v = make_int4(c.x + 9, c.y + 9, c.z + 9, c.w + 9);
    if (x > 0) {
        int4 m = src[i - PL_ / 4];
        v.x = min(v.x, m.x + 18); v.y = min(v.y, m.y + 18);
        v.z = min(v.z, m.z + 18); v.w = min(v.w, m.w + 18);
    }
    if (x < S_ - 1) {
        int4 pp = src[i + PL_ / 4];
        v.x = min(v.x, pp.x); v.y = min(v.y, pp.y);
        v.z = min(v.z, pp.z); v.w = min(v.w, pp.w);
    }
    dst[i] = v;
}

// THE random pass: idx = cell(bpt[p]) + klin(k) (pure arithmetic k-offset),
// gather m32, ballot -> bitmap, store m32 to mArr; out0/out2 fills ride
// under the fetch-bound gather.
__global__ __launch_bounds__(256) void k_gather(const int* __restrict__ bpt,
                                                const int* __restrict__ M,
                                                int* __restrict__ mArr,
                                                unsigned long long* __restrict__ bitmap,
                                                int* __restrict__ out0,
                                                int* __restrict__ out2) {
    int l = blockIdx.x * blockDim.x + threadIdx.x;
    if (l >= L_) return;
    int p = l / K_;
    int k = l - p * K_;
    out0[l] = p - (p / N_) * N_;   // n
    out2[l] = k;
    unsigned u = (unsigned)bpt[p];
    int b = u >> 24, x = (u >> 16) & 255, y = (u >> 8) & 255, z = u & 255;
    int dx = k / 9, dy = (k / 3) % 3, dz = k - (k / 3) * 3;
    int cx = x + dx - 1, cy = y + dy - 1, cz = z + dz - 1;   // 0..129
    int idx = ((b * S_ + cx) * S_ + cy) * S_ + cz;
    int m32 = M[idx];
    mArr[l] = m32;
    unsigned long long bal = __ballot(m32 == ((p << 5) | k));
    if ((threadIdx.x & 63) == 0) bitmap[l >> 6] = bal;
}

// per-word popcount + per-block exclusive scan over 84375 words
__global__ __launch_bounds__(256) void k_scan_words(const unsigned long long* __restrict__ bitmap,
                                                    int* __restrict__ wpre,
                                                    int* __restrict__ bsum) {
    __shared__ int sh[256];
    int w = blockIdx.x * 256 + threadIdx.x;
    int c = (w < W_) ? __popcll(bitmap[w]) : 0;
    sh[threadIdx.x] = c;
    __syncthreads();
    for (int off = 1; off < 256; off <<= 1) {
        int t = (threadIdx.x >= off) ? sh[threadIdx.x - off] : 0;
        __syncthreads();
        sh[threadIdx.x] += t;
        __syncthreads();
    }
    if (w < W_) wpre[w] = sh[threadIdx.x] - c;        // exclusive within block
    if (threadIdx.x == 255) bsum[blockIdx.x] = sh[255];
}

// single-block exclusive scan over the 330 block sums; emits num_unique
__global__ __launch_bounds__(512) void k_scan_block(int* __restrict__ bsum,
                                                    int* __restrict__ num_unique_out) {
    __shared__ int sh[512];
    int i = threadIdx.x;
    int v = (i < NBW) ? bsum[i] : 0;
    sh[i] = v;
    __syncthreads();
    for (int off = 1; off < 512; off <<= 1) {
        int t = (i >= off) ? sh[i - off] : 0;
        __syncthreads();
        sh[i] += t;
        __syncthreads();
    }
    if (i < NBW) bsum[i] = sh[i] - v;                 // global exclusive prefix
    if (i == 0) num_unique_out[0] = sh[511];
}

// rank via bitmap popcount (bitmap+wpre ~1.3MB, L2-resident); valid outkey
// rows written once; tail rows (>= num_unique) written -1 here (disjoint).
__global__ __launch_bounds__(256) void k_finalize(const int* __restrict__ coords,
                                                  const int* __restrict__ koffs,
                                                  const unsigned long long* __restrict__ bitmap,
                                                  const int* __restrict__ wpre,
                                                  const int* __restrict__ bsum,
                                                  const int* __restrict__ numuniq,
                                                  int* __restrict__ out1,   // holds m32, becomes output_idx
                                                  int* __restrict__ outkey) {
    int l = blockIdx.x * blockDim.x + threadIdx.x;
    if (l >= L_) return;
    int m32 = out1[l];
    int m = (m32 >> 5) * K_ + (m32 & 31);
    int w = m >> 6;
    unsigned long long word = bitmap[w];
    unsigned long long mask = (1ull << (m & 63)) - 1ull;
    int rank = wpre[w] + bsum[w >> 8] + (int)__popcll(word & mask);
    out1[l] = rank;
    if (m == l) {
        int p = l / K_;
        int k = l - p * K_;
        outkey[3 * rank + 0] = coords[3 * p + 0] + koffs[3 * k + 0];
        outkey[3 * rank + 1] = coords[3 * p + 1] + koffs[3 * k + 1];
        outkey[3 * rank + 2] = coords[3 * p + 2] + koffs[3 * k + 2];
    }
    if (l >= numuniq[0]) {
        outkey[3 * l + 0] = -1;
        outkey[3 * l + 1] = -1;
        outkey[3 * l + 2] = -1;
    }
}

extern "C" void kernel_launch(void* const* d_in, const int* in_sizes, int n_in,
                              void* d_out, int out_size, void* d_ws, size_t ws_size,
                              hipStream_t stream) {
    const int* coords = (const int*)d_in[0];   // [B,N,3] int32
    const int* bidx   = (const int*)d_in[1];   // [B,N]   int32
    const int* koffs  = (const int*)d_in[2];   // [27,3]  int32

    int* out      = (int*)d_out;
    int* out0     = out;            // input_idx      [L]
    int* out1     = out + L_;       // output_idx     [L] (holds m32 first)
    int* out2     = out + 2 * L_;   // rel_pos_idx    [L]
    int* outkey   = out + 3 * L_;   // output_key     [L,3]
    int* numuniq  = out + 6 * L_;   // num_unique     [1]

    // ws (~37 MB): P1 | bitmap | wpre | bsum | bpt
    int* P1 = (int*)d_ws;                                         // KS_ ints
    unsigned long long* bitmap = (unsigned long long*)(P1 + KS_); // W_ u64 (8B aligned)
    int* wpre = (int*)(bitmap + W_);                              // W_ ints
    int* bsum = wpre + W_;                                        // NBW ints
    int* bpt  = bsum + NBW;                                       // P_ ints

    // stencil ping-pong scratch A in the (not-yet-written) outkey region:
    // KS_ ints <= 3*L_ ints; fully consumed by k_x before k_finalize writes outkey.
    int* A = outkey;

    k_init       <<<2048, 256, 0, stream>>>((int4*)P1);
    k_ptab       <<<(P_ + 255) / 256, 256, 0, stream>>>(coords, bidx, P1, bpt);
    k_zy         <<<B_ * S_, 512, 0, stream>>>(P1, A);                      // P1 -> A
    k_x          <<<(KS_ / 4 + 255) / 256, 256, 0, stream>>>((const int4*)A, (int4*)P1);
    k_gather     <<<(L_ + 255) / 256, 256, 0, stream>>>(bpt, P1, out1, bitmap, out0, out2);
    k_scan_words <<<NBW, 256, 0, stream>>>(bitmap, wpre, bsum);
    k_scan_block <<<1, 512, 0, stream>>>(bsum, numuniq);
    k_finalize   <<<(L_ + 255) / 256, 256, 0, stream>>>(coords, koffs, bitmap, wpre, bsum,
                                                        numuniq, out1, outkey);
}